// Round 1
// baseline (63.725 us; speedup 1.0000x reference)
//
#include <hip/hip_runtime.h>

// out[b] = cos(x[b,0]).
//
// Derivation: initial state is a real product state (per-wire normalized
// [cos(x_i/2), sin(x_i/2)]). RZ layers are unit-modulus diagonal phases
// (magnitude-preserving); CNOTs are amplitude permutations whose targets are
// wires 1..3 only, so the wire-0 bit of every basis index is invariant.
// |state|^2 is thus the initial probability tensor permuted within the
// (b1,b2,b3) sub-index for each fixed b0; summing probs * (-1)^{b0}
// marginalizes wires 1..3 (each sums to 1) leaving
// cos^2(x0/2) - sin^2(x0/2) = cos(x0). Weight cancels entirely.
//
// This version: 4 batch elements per thread, vectorized float4 output store.
// 1M elems -> 262144 threads -> 1024 blocks of 256. Cuts wave count 4x and
// store instructions 4x vs the 1-elem/thread version (which was ~20x above
// the ~3.3 us memory roofline -> overhead-bound, not BW-bound).

__global__ __launch_bounds__(256) void quanv_cos_kernel(
    const float4* __restrict__ x,   // (B,4) viewed as B float4s
    float4* __restrict__ out,       // (B,) viewed as B/4 float4s
    int n4)                         // B/4
{
    int i = blockIdx.x * blockDim.x + threadIdx.x;
    if (i < n4) {
        // Rows 4i..4i+3; we only need the .x lane of each, but the full
        // lines are fetched by HW regardless (stride-16B touches every line).
        float4 a = x[4 * i + 0];
        float4 b = x[4 * i + 1];
        float4 c = x[4 * i + 2];
        float4 d = x[4 * i + 3];
        out[i] = make_float4(cosf(a.x), cosf(b.x), cosf(c.x), cosf(d.x));
    }
}

extern "C" void kernel_launch(void* const* d_in, const int* in_sizes, int n_in,
                              void* d_out, int out_size, void* d_ws, size_t ws_size,
                              hipStream_t stream) {
    const float4* x = (const float4*)d_in[0];   // (B,4) fp32
    float4* out = (float4*)d_out;               // (B,) fp32, B % 4 == 0
    int n = out_size;                           // B = 1048576
    int n4 = n / 4;

    const int block = 256;
    const int grid = (n4 + block - 1) / block;  // 1024 blocks
    quanv_cos_kernel<<<grid, block, 0, stream>>>(x, out, n4);
}